// Round 1
// 683.541 us; speedup vs baseline: 1.0692x; 1.0692x over previous
//
#include <hip/hip_runtime.h>

typedef unsigned short u16;
typedef unsigned int u32;
typedef float f32x4 __attribute__((ext_vector_type(4)));
typedef __bf16 bf16x8 __attribute__((ext_vector_type(8)));

#define F 256
#define T_OUT 8
#define N_MONO 150000
#define N_CLEAV 100000
#define N_FRAG 80000
#define N_OUT 40000
#define M_CLEAV_PAD 100352   // 392 * 256

static __device__ __forceinline__ u16 f2bf(float f) {
  u32 u = __float_as_uint(f);
  u32 r = (u + 0x7FFFu + ((u >> 16) & 1u)) >> 16;
  return (u16)r;
}
static __device__ __forceinline__ float bf2f(u16 b) {
  return __uint_as_float(((u32)b) << 16);
}
static __device__ __forceinline__ float sigmoidf(float x) {
  return __frcp_rn(1.0f + __expf(-x));
}
static __device__ __forceinline__ float fast_tanh(float x) {
  return 1.0f - 2.0f * __frcp_rn(__expf(2.0f * x) + 1.0f);
}
static __device__ __forceinline__ void async_copy16(const u16* g, const u16* l) {
  __builtin_amdgcn_global_load_lds(
      (const __attribute__((address_space(1))) u32*)g,
      (__attribute__((address_space(3))) u32*)l,
      16, 0, 0);
}

// ---------------- K0: weight cast + bias sum ----------------
__global__ __launch_bounds__(256) void prep_kernel(
    const float* __restrict__ Wih, const float* __restrict__ Whh,
    const float* __restrict__ bih, const float* __restrict__ bhh,
    u16* __restrict__ Wihb, u16* __restrict__ Whhb, float* __restrict__ bias) {
  int i = blockIdx.x * 256 + threadIdx.x;
  if (i < 1024 * 512) Wihb[i] = f2bf(Wih[i]);
  if (i < 1024 * 256) Whhb[i] = f2bf(Whh[i]);
  if (i < 1024) bias[i] = bih[i] + bhh[i];
}

// ---------------- K1: attention pulls -> cleav [N_CLEAV, 512] bf16 --------
__global__ __launch_bounds__(256) void attn_pull(
    const float* __restrict__ feat, const float* __restrict__ WgL,
    const float* __restrict__ WgR, const int* __restrict__ lostS,
    const int* __restrict__ retS, u16* __restrict__ cleav) {
  int wave = threadIdx.x >> 6, lane = threadIdx.x & 63;
  int n = blockIdx.x * 4 + wave;
  if (n >= N_CLEAV) return;
  const float4 wgl = *(const float4*)(WgL + lane * 4);
  const float4 wgr = *(const float4*)(WgR + lane * 4);
  for (int sg = 0; sg < 2; ++sg) {
    const int* src = sg ? retS : lostS;
    float4 wg = sg ? wgr : wgl;
    int4 ridx = *(const int4*)(src + n * 4);
    int r[4] = {ridx.x, ridx.y, ridx.z, ridx.w};
    float4 x[4];
#pragma unroll
    for (int d = 0; d < 4; ++d)
      x[d] = *(const float4*)(feat + (size_t)r[d] * F + lane * 4);
    float logit[4];
#pragma unroll
    for (int d = 0; d < 4; ++d) {
      float p = x[d].x * wg.x + x[d].y * wg.y + x[d].z * wg.z + x[d].w * wg.w;
#pragma unroll
      for (int off = 32; off; off >>= 1) p += __shfl_xor(p, off);
      logit[d] = p;
    }
    float mx = fmaxf(fmaxf(logit[0], logit[1]), fmaxf(logit[2], logit[3]));
    float e0 = __expf(logit[0] - mx), e1 = __expf(logit[1] - mx);
    float e2 = __expf(logit[2] - mx), e3 = __expf(logit[3] - mx);
    float inv = 1.f / (e0 + e1 + e2 + e3);
    float a0 = e0 * inv, a1 = e1 * inv, a2 = e2 * inv, a3 = e3 * inv;
    float4 acc;
    acc.x = a0 * x[0].x + a1 * x[1].x + a2 * x[2].x + a3 * x[3].x;
    acc.y = a0 * x[0].y + a1 * x[1].y + a2 * x[2].y + a3 * x[3].y;
    acc.z = a0 * x[0].z + a1 * x[1].z + a2 * x[2].z + a3 * x[3].z;
    acc.w = a0 * x[0].w + a1 * x[1].w + a2 * x[2].w + a3 * x[3].w;
    u32 lo = (u32)f2bf(acc.x) | ((u32)f2bf(acc.y) << 16);
    u32 hi = (u32)f2bf(acc.z) | ((u32)f2bf(acc.w) << 16);
    *(uint2*)(cleav + (size_t)n * 512 + sg * 256 + lane * 4) = make_uint2(lo, hi);
  }
}

// ---------------- GEMM: C[M,1024] = A[M,K] * B[1024,K]^T ------------------
// 256x256 tile, BK=64, 8 waves (2M x 4N), 128 KiB LDS double-buffered at
// K-tile granularity. 4 quadrant phases per K-tile (16 MFMA each), per-phase
// {ds_read subtile | 1 half-tile global_load_lds} -> barrier -> lgkmcnt(0)
// -> setprio(1) MFMA setprio(0) -> barrier.  Counted vmcnt(4) only at the
// tile boundary (2 half-tiles of 2 loads stay in flight across it).
// LDS swizzle: physical k-chunk = logical ^ (row&7); row stride 128 B == 32
// banks so bank index depends only on the chunk -> 2-way aliasing (free).
// Staging keeps LDS dest linear (global_load_lds) and pre-swizzles the
// GLOBAL source; reads apply the same involution.
// Staging schedule (computing tile t from buf t&1):
//   ph1: stage A-half0(t+1)->buf^1   (A region of buf^1 free since ph3(t-1))
//   ph2: stage A-half1(t+1)->buf^1
//   ph3: stage B-half0(t+2)->buf     (B region of buf free after ph2(t) end)
//   ph4: stage B-half1(t+2)->buf
// EPI==0: C = acc + bias[n]; EPI==1: C = acc.
template <int EPI, int K>
__global__ __launch_bounds__(512, 2) void gemm256(
    const u16* __restrict__ A, const u16* __restrict__ Bw,
    u16* __restrict__ C, const float* __restrict__ bias,
    int nper, int mstrips_valid) {
  __shared__ u16 sh[2][32768];  // [buf][A:0..16383 | B:16384..32767]
  const int flat = blockIdx.x;
  const int xcd = flat & 7;
  const int w = flat >> 3;
  const int mstrip = xcd * nper + (w >> 2);
  const int nstrip = w & 3;
  if (mstrip >= mstrips_valid) return;
  const int m0 = mstrip * 256;
  const int n0 = nstrip * 256;

  const int tid = threadIdx.x;
  const int lane = tid & 63;
  const int wave = tid >> 6;
  const int quad = lane >> 4;
  const int l16 = lane & 15;
  const int s7 = l16 & 7;
  const int wm2 = wave >> 2;  // 0..1 -> 128-row half
  const int wn4 = wave & 3;   // 0..3 -> 64-col slice

  // read bases (u16 units inside one buffer)
  const int arow = (wm2 * 128 + l16) * 64;
  const int brow = 16384 + (wn4 * 64 + l16) * 64;
  const int coff0 = ((0 + quad) ^ s7) * 8;  // k-step 0 chunk
  const int coff1 = ((4 + quad) ^ s7) * 8;  // k-step 1 chunk

  // staging precompute: chunk c = j*512 + tid; r=c>>3 row, p=c&7 phys chunk
  int srow[2], ssw[2], sdst[2];
#pragma unroll
  for (int j = 0; j < 2; j++) {
    int c = j * 512 + tid;
    int r = c >> 3, p = c & 7;
    srow[j] = r;
    ssw[j] = (p ^ (r & 7)) * 8;              // pre-swizzled global k-offset
    sdst[j] = (j * 512 + (tid & ~63)) * 8;   // wave-uniform; HW adds lane*16B
  }
  const u16* Abase = A + (size_t)m0 * K;
  const u16* Bbase = Bw + (size_t)n0 * K;

  auto stage = [&](int buf, int mat, int h, int kt) {
    const u16* gb = (mat ? Bbase : Abase) + (size_t)(h * 128) * K + kt * 64;
    const u16* lb = &sh[buf][mat * 16384 + h * 8192];
#pragma unroll
    for (int j = 0; j < 2; j++)
      async_copy16(gb + (size_t)srow[j] * K + ssw[j], lb + sdst[j]);
  };

  f32x4 acc[8][4];
#pragma unroll
  for (int i = 0; i < 8; i++)
#pragma unroll
    for (int j = 0; j < 4; j++) acc[i][j] = (f32x4){0.f, 0.f, 0.f, 0.f};

  constexpr int nK = K / 64;
  // prologue: tile0 fully -> buf0; tile1 B halves -> buf1 (A halves follow
  // in-loop at phases 1-2 of tile 0).
  stage(0, 0, 0, 0); stage(0, 0, 1, 0); stage(0, 1, 0, 0); stage(0, 1, 1, 0);
  if (nK > 1) { stage(1, 1, 0, 1); stage(1, 1, 1, 1); }
  __builtin_amdgcn_s_waitcnt(0xF74);  // vmcnt(4): tile0 landed, tile1-B in flight
  __builtin_amdgcn_s_barrier();

  bf16x8 a[4][2], b0[2][2], b1[2][2];
#pragma unroll
  for (int t = 0; t < nK; ++t) {
    const int bsel = t & 1;
    const u16* S = &sh[bsel][0];

    // ---- phase 1: Q(qm=0,qn=0). 12 ds_read_b128; stage A-half0(t+1).
#pragma unroll
    for (int i = 0; i < 4; i++) {
      a[i][0] = *(const bf16x8*)&S[arow + i * 1024 + coff0];
      a[i][1] = *(const bf16x8*)&S[arow + i * 1024 + coff1];
    }
#pragma unroll
    for (int j = 0; j < 2; j++) {
      b0[j][0] = *(const bf16x8*)&S[brow + j * 1024 + coff0];
      b0[j][1] = *(const bf16x8*)&S[brow + j * 1024 + coff1];
    }
    if (t + 1 < nK) stage(bsel ^ 1, 0, 0, t + 1);
    __builtin_amdgcn_s_waitcnt(0xC87F);  // lgkmcnt(8) pre-barrier (12 issued)
    __builtin_amdgcn_s_barrier();
    __builtin_amdgcn_s_waitcnt(0xC07F);  // lgkmcnt(0)
    __builtin_amdgcn_sched_barrier(0);
    __builtin_amdgcn_s_setprio(1);
#pragma unroll
    for (int i = 0; i < 4; i++)
#pragma unroll
      for (int j = 0; j < 2; j++) {
        acc[i][j] = __builtin_amdgcn_mfma_f32_16x16x32_bf16(a[i][0], b0[j][0], acc[i][j], 0, 0, 0);
        acc[i][j] = __builtin_amdgcn_mfma_f32_16x16x32_bf16(a[i][1], b0[j][1], acc[i][j], 0, 0, 0);
      }
    __builtin_amdgcn_s_setprio(0);
    __builtin_amdgcn_s_barrier();

    // ---- phase 2: Q(0,1). 4 ds_read; stage A-half1(t+1).
#pragma unroll
    for (int j = 0; j < 2; j++) {
      b1[j][0] = *(const bf16x8*)&S[brow + (2 + j) * 1024 + coff0];
      b1[j][1] = *(const bf16x8*)&S[brow + (2 + j) * 1024 + coff1];
    }
    if (t + 1 < nK) stage(bsel ^ 1, 0, 1, t + 1);
    __builtin_amdgcn_s_barrier();
    __builtin_amdgcn_s_waitcnt(0xC07F);
    __builtin_amdgcn_sched_barrier(0);
    __builtin_amdgcn_s_setprio(1);
#pragma unroll
    for (int i = 0; i < 4; i++)
#pragma unroll
      for (int j = 0; j < 2; j++) {
        acc[i][2 + j] = __builtin_amdgcn_mfma_f32_16x16x32_bf16(a[i][0], b1[j][0], acc[i][2 + j], 0, 0, 0);
        acc[i][2 + j] = __builtin_amdgcn_mfma_f32_16x16x32_bf16(a[i][1], b1[j][1], acc[i][2 + j], 0, 0, 0);
      }
    __builtin_amdgcn_s_setprio(0);
    __builtin_amdgcn_s_barrier();

    // ---- phase 3: Q(1,0). 8 ds_read (reuse a[]); stage B-half0(t+2)->buf bsel.
#pragma unroll
    for (int i = 0; i < 4; i++) {
      a[i][0] = *(const bf16x8*)&S[arow + (4 + i) * 1024 + coff0];
      a[i][1] = *(const bf16x8*)&S[arow + (4 + i) * 1024 + coff1];
    }
    if (t + 2 < nK) stage(bsel, 1, 0, t + 2);
    __builtin_amdgcn_s_barrier();
    __builtin_amdgcn_s_waitcnt(0xC07F);
    __builtin_amdgcn_sched_barrier(0);
    __builtin_amdgcn_s_setprio(1);
#pragma unroll
    for (int i = 0; i < 4; i++)
#pragma unroll
      for (int j = 0; j < 2; j++) {
        acc[4 + i][j] = __builtin_amdgcn_mfma_f32_16x16x32_bf16(a[i][0], b0[j][0], acc[4 + i][j], 0, 0, 0);
        acc[4 + i][j] = __builtin_amdgcn_mfma_f32_16x16x32_bf16(a[i][1], b0[j][1], acc[4 + i][j], 0, 0, 0);
      }
    __builtin_amdgcn_s_setprio(0);
    __builtin_amdgcn_s_barrier();

    // ---- phase 4: Q(1,1). 0 ds_read; stage B-half1(t+2); boundary vmcnt.
    if (t + 2 < nK) stage(bsel, 1, 1, t + 2);
    __builtin_amdgcn_s_barrier();
    __builtin_amdgcn_s_setprio(1);
#pragma unroll
    for (int i = 0; i < 4; i++)
#pragma unroll
      for (int j = 0; j < 2; j++) {
        acc[4 + i][2 + j] = __builtin_amdgcn_mfma_f32_16x16x32_bf16(a[i][0], b1[j][0], acc[4 + i][2 + j], 0, 0, 0);
        acc[4 + i][2 + j] = __builtin_amdgcn_mfma_f32_16x16x32_bf16(a[i][1], b1[j][1], acc[4 + i][2 + j], 0, 0, 0);
      }
    __builtin_amdgcn_s_setprio(0);
    // all but the 2 newest half-tiles (Bh(t+2)) must be landed before any
    // wave reads buf^1; in the drain tiles (no t+2 stages) drain fully.
    if (t + 2 < nK) __builtin_amdgcn_s_waitcnt(0xF74);  // vmcnt(4)
    else            __builtin_amdgcn_s_waitcnt(0xF70);  // vmcnt(0)
    __builtin_amdgcn_s_barrier();
  }

  // epilogue: C/D layout col=lane&15, row=quad*4+reg
  float badd[4];
#pragma unroll
  for (int j = 0; j < 4; j++)
    badd[j] = (EPI == 0) ? bias[n0 + wn4 * 64 + j * 16 + l16] : 0.f;
#pragma unroll
  for (int i = 0; i < 8; i++) {
    const int mrow = m0 + wm2 * 128 + i * 16 + quad * 4;
#pragma unroll
    for (int j = 0; j < 4; j++) {
      const int n = n0 + wn4 * 64 + j * 16 + l16;
#pragma unroll
      for (int r = 0; r < 4; r++)
        C[(size_t)(mrow + r) * 1024 + n] = f2bf(acc[i][j][r] + badd[j]);
    }
  }
}

// ---------------- K3: LSTM step 1, wave-per-fragment ----------------------
__global__ __launch_bounds__(256) void lstm_step1(
    const u16* __restrict__ P, const int* __restrict__ join,
    u16* __restrict__ h1, u16* __restrict__ c1) {
  int wave = threadIdx.x >> 6, lane = threadIdx.x & 63;
  int m = blockIdx.x * 4 + wave;
  if (m >= N_FRAG) return;
  int j0 = join[2 * m];
  const u16* row = P + (size_t)j0 * 1024 + lane * 4;
  ushort4 iv = *(const ushort4*)(row);
  ushort4 gv = *(const ushort4*)(row + 512);
  ushort4 ov = *(const ushort4*)(row + 768);
  const u16* ivp = (const u16*)&iv;
  const u16* gvp = (const u16*)&gv;
  const u16* ovp = (const u16*)&ov;
  ushort4 h4, c4;
  u16* h4p = (u16*)&h4;
  u16* c4p = (u16*)&c4;
#pragma unroll
  for (int k = 0; k < 4; k++) {
    float c = sigmoidf(bf2f(ivp[k])) * fast_tanh(bf2f(gvp[k]));
    float hv = sigmoidf(bf2f(ovp[k])) * fast_tanh(c);
    h4p[k] = f2bf(hv);
    c4p[k] = f2bf(c);
  }
  *(ushort4*)(h1 + (size_t)m * 256 + lane * 4) = h4;
  *(ushort4*)(c1 + (size_t)m * 256 + lane * 4) = c4;
}

// ------- K5: LSTM step 2 + attention over {h1,h2} + output head -----------
__global__ __launch_bounds__(256) void lstm_step2_attn_out(
    const u16* __restrict__ G2, const u16* __restrict__ P,
    const int* __restrict__ join, const u16* __restrict__ c1,
    const u16* __restrict__ h1b, const float* __restrict__ Wg,
    const float* __restrict__ Wout, const float* __restrict__ bout,
    float* __restrict__ frag_out) {
  int wave = threadIdx.x >> 6, lane = threadIdx.x & 63;
  int m = blockIdx.x * 4 + wave;
  if (m >= N_FRAG) return;
  int j1 = join[2 * m + 1];
  const u16* row = G2 + (size_t)m * 1024 + lane * 4;
  const u16* prow = P + (size_t)j1 * 1024 + lane * 4;
  ushort4 iv = *(const ushort4*)(row);
  ushort4 fv = *(const ushort4*)(row + 256);
  ushort4 gv = *(const ushort4*)(row + 512);
  ushort4 ov = *(const ushort4*)(row + 768);
  ushort4 pi = *(const ushort4*)(prow);
  ushort4 pf = *(const ushort4*)(prow + 256);
  ushort4 pg = *(const ushort4*)(prow + 512);
  ushort4 po = *(const ushort4*)(prow + 768);
  ushort4 c4 = *(const ushort4*)(c1 + (size_t)m * 256 + lane * 4);
  ushort4 h4 = *(const ushort4*)(h1b + (size_t)m * 256 + lane * 4);
  float4 wg = *(const float4*)(Wg + lane * 4);
  const u16* ivp = (const u16*)&iv; const u16* pip = (const u16*)&pi;
  const u16* fvp = (const u16*)&fv; const u16* pfp = (const u16*)&pf;
  const u16* gvp = (const u16*)&gv; const u16* pgp = (const u16*)&pg;
  const u16* ovp = (const u16*)&ov; const u16* pop = (const u16*)&po;
  const u16* c4p = (const u16*)&c4;
  const u16* h4p = (const u16*)&h4;
  const float* wgp = (const float*)&wg;

  float h1v[4], h2v[4];
  float p1 = 0.f, p2 = 0.f;
#pragma unroll
  for (int k = 0; k < 4; k++) {
    float gi = bf2f(ivp[k]) + bf2f(pip[k]);
    float gf = bf2f(fvp[k]) + bf2f(pfp[k]);
    float gg = bf2f(gvp[k]) + bf2f(pgp[k]);
    float go = bf2f(ovp[k]) + bf2f(pop[k]);
    float c2 = sigmoidf(gf) * bf2f(c4p[k]) + sigmoidf(gi) * fast_tanh(gg);
    float h2 = sigmoidf(go) * fast_tanh(c2);
    h2v[k] = h2;
    h1v[k] = bf2f(h4p[k]);
    p1 += h1v[k] * wgp[k];
    p2 += h2 * wgp[k];
  }
#pragma unroll
  for (int off = 32; off; off >>= 1) {
    p1 += __shfl_xor(p1, off);
    p2 += __shfl_xor(p2, off);
  }
  float mx = fmaxf(p1, p2);
  float e1 = __expf(p1 - mx), e2 = __expf(p2 - mx);
  float inv = __frcp_rn(e1 + e2);
  float a1 = e1 * inv, a2 = e2 * inv;

  float acc[8];
#pragma unroll
  for (int t = 0; t < 8; t++) acc[t] = 0.f;
#pragma unroll
  for (int k = 0; k < 4; k++) {
    float frag = a1 * h1v[k] + a2 * h2v[k];
    int h = lane * 4 + k;
    float4 w0 = *(const float4*)(Wout + h * 8);
    float4 w1 = *(const float4*)(Wout + h * 8 + 4);
    acc[0] += frag * w0.x; acc[1] += frag * w0.y;
    acc[2] += frag * w0.z; acc[3] += frag * w0.w;
    acc[4] += frag * w1.x; acc[5] += frag * w1.y;
    acc[6] += frag * w1.z; acc[7] += frag * w1.w;
  }
#pragma unroll
  for (int off = 32; off; off >>= 1)
#pragma unroll
    for (int t = 0; t < 8; t++) acc[t] += __shfl_xor(acc[t], off);
  if (lane == 0) {
    float4 o0, o1;
    o0.x = fmaxf(acc[0] + bout[0], 0.f);
    o0.y = fmaxf(acc[1] + bout[1], 0.f);
    o0.z = fmaxf(acc[2] + bout[2], 0.f);
    o0.w = fmaxf(acc[3] + bout[3], 0.f);
    o1.x = fmaxf(acc[4] + bout[4], 0.f);
    o1.y = fmaxf(acc[5] + bout[5], 0.f);
    o1.z = fmaxf(acc[6] + bout[6], 0.f);
    o1.w = fmaxf(acc[7] + bout[7], 0.f);
    *(float4*)(frag_out + (size_t)m * 8) = o0;
    *(float4*)(frag_out + (size_t)m * 8 + 4) = o1;
  }
}

// ---------------- K6: combine scatter-sum ---------------------------------
__global__ __launch_bounds__(256) void scatter_sum(
    const float* __restrict__ frag_out, const int* __restrict__ comb,
    float* __restrict__ out) {
  int tid = blockIdx.x * 256 + threadIdx.x;
  if (tid >= N_OUT * 8) return;
  int n = tid >> 3, t = tid & 7;
  float s = 0.f;
#pragma unroll
  for (int d = 0; d < 4; d++) {
    int f = comb[n * 4 + d];
    s += frag_out[(size_t)f * 8 + t];
  }
  out[tid] = s;
}

extern "C" void kernel_launch(void* const* d_in, const int* in_sizes, int n_in,
                              void* d_out, int out_size, void* d_ws, size_t ws_size,
                              hipStream_t stream) {
  const float* feature = (const float*)d_in[0];
  const float* WgL = (const float*)d_in[1];
  const float* WgR = (const float*)d_in[2];
  const float* Wih = (const float*)d_in[3];
  const float* Whh = (const float*)d_in[4];
  const float* bih = (const float*)d_in[5];
  const float* bhh = (const float*)d_in[6];
  const float* Wgf = (const float*)d_in[7];
  const float* Wout = (const float*)d_in[8];
  const float* bout = (const float*)d_in[9];
  const int* lostS = (const int*)d_in[10];
  const int* retS = (const int*)d_in[11];
  const int* joinS = (const int*)d_in[12];
  const int* combS = (const int*)d_in[13];
  float* out = (float*)d_out;

  char* ws = (char*)d_ws;
  size_t off = 0;
  auto alloc = [&](size_t bytes) -> char* {
    char* p = ws + off;
    off = (off + bytes + 255) & ~(size_t)255;
    return p;
  };
  u16* Wihb = (u16*)alloc((size_t)1024 * 512 * 2);
  u16* Whhb = (u16*)alloc((size_t)1024 * 256 * 2);
  float* bias = (float*)alloc(1024 * 4);
  u16* P = (u16*)alloc((size_t)M_CLEAV_PAD * 1024 * 2);
  u16* h1 = (u16*)alloc((size_t)N_FRAG * 256 * 2);
  u16* c1 = (u16*)alloc((size_t)N_FRAG * 256 * 2);
  float* frag_out = (float*)alloc((size_t)N_FRAG * 8 * 4);
  char* uni = alloc((size_t)M_CLEAV_PAD * 1024 * 2);  // cleav then gates2
  u16* cleav = (u16*)uni;
  u16* gates2 = (u16*)uni;

  prep_kernel<<<2048, 256, 0, stream>>>(Wih, Whh, bih, bhh, Wihb, Whhb, bias);
  attn_pull<<<N_CLEAV / 4, 256, 0, stream>>>(feature, WgL, WgR, lostS, retS, cleav);
  // GEMM-1: M=100352=392*256 strips, 49 per XCD, all valid
  gemm256<0, 512><<<1568, 512, 0, stream>>>(cleav, Wihb, P, bias, 49, 392);
  lstm_step1<<<N_FRAG / 4, 256, 0, stream>>>(P, joinS, h1, c1);
  // GEMM-2: M=80000 -> 313 strips of 256 (rows 80000..80127 read c1 garbage,
  // row-independent so harmless; output rows >=80000 never consumed).
  // 320 virtual strips (40/XCD), tail early-exits.
  gemm256<1, 256><<<1280, 512, 0, stream>>>(h1, Whhb, gates2, nullptr, 40, 313);
  lstm_step2_attn_out<<<N_FRAG / 4, 256, 0, stream>>>(
      gates2, P, joinS, c1, h1, Wgf, Wout, bout, frag_out);
  scatter_sum<<<(N_OUT * 8 + 255) / 256, 256, 0, stream>>>(frag_out, combS, out);
}

// Round 2
// 659.533 us; speedup vs baseline: 1.1081x; 1.0364x over previous
//
#include <hip/hip_runtime.h>

typedef unsigned short u16;
typedef unsigned int u32;
typedef float f32x4 __attribute__((ext_vector_type(4)));
typedef __bf16 bf16x8 __attribute__((ext_vector_type(8)));

#define F 256
#define T_OUT 8
#define N_MONO 150000
#define N_CLEAV 100000
#define N_FRAG 80000
#define N_OUT 40000
#define M_CLEAV_PAD 100352   // 392 * 256

static __device__ __forceinline__ u16 f2bf(float f) {
  u32 u = __float_as_uint(f);
  u32 r = (u + 0x7FFFu + ((u >> 16) & 1u)) >> 16;
  return (u16)r;
}
static __device__ __forceinline__ float bf2f(u16 b) {
  return __uint_as_float(((u32)b) << 16);
}
static __device__ __forceinline__ float sigmoidf(float x) {
  return __frcp_rn(1.0f + __expf(-x));
}
static __device__ __forceinline__ float fast_tanh(float x) {
  return 1.0f - 2.0f * __frcp_rn(__expf(2.0f * x) + 1.0f);
}
static __device__ __forceinline__ void async_copy16(const u16* g, const u16* l) {
  __builtin_amdgcn_global_load_lds(
      (const __attribute__((address_space(1))) u32*)g,
      (__attribute__((address_space(3))) u32*)l,
      16, 0, 0);
}

// ---------------- K0: weight cast + bias sum ----------------
__global__ __launch_bounds__(256) void prep_kernel(
    const float* __restrict__ Wih, const float* __restrict__ Whh,
    const float* __restrict__ bih, const float* __restrict__ bhh,
    u16* __restrict__ Wihb, u16* __restrict__ Whhb, float* __restrict__ bias) {
  int i = blockIdx.x * 256 + threadIdx.x;
  if (i < 1024 * 512) Wihb[i] = f2bf(Wih[i]);
  if (i < 1024 * 256) Whhb[i] = f2bf(Whh[i]);
  if (i < 1024) bias[i] = bih[i] + bhh[i];
}

// ------- K0b: stream feature -> bf16 copy + per-mono gate logits ----------
// glog[n][0] = feature[n]·WgL ; glog[n][1] = feature[n]·WgR (exact f32).
// One wave per mono row; fully coalesced read/write, shuffle reduce here
// (streaming-bound kernel) so the gather kernel needs none.
__global__ __launch_bounds__(256) void feat_prep(
    const float* __restrict__ feat, const float* __restrict__ WgL,
    const float* __restrict__ WgR, u16* __restrict__ featb,
    float* __restrict__ glog) {
  int wave = threadIdx.x >> 6, lane = threadIdx.x & 63;
  int n = blockIdx.x * 4 + wave;
  if (n >= N_MONO) return;
  float4 x = *(const float4*)(feat + (size_t)n * F + lane * 4);
  u32 lo = (u32)f2bf(x.x) | ((u32)f2bf(x.y) << 16);
  u32 hi = (u32)f2bf(x.z) | ((u32)f2bf(x.w) << 16);
  *(uint2*)(featb + (size_t)n * F + lane * 4) = make_uint2(lo, hi);
  float4 wl = *(const float4*)(WgL + lane * 4);
  float4 wr = *(const float4*)(WgR + lane * 4);
  float pl = x.x * wl.x + x.y * wl.y + x.z * wl.z + x.w * wl.w;
  float pr = x.x * wr.x + x.y * wr.y + x.z * wr.z + x.w * wr.w;
#pragma unroll
  for (int off = 32; off; off >>= 1) {
    pl += __shfl_xor(pl, off);
    pr += __shfl_xor(pr, off);
  }
  if (lane == 0) {
    glog[n * 2] = pl;
    glog[n * 2 + 1] = pr;
  }
}

// ---------------- K1: attention pulls -> cleav [N_CLEAV, 512] bf16 --------
// Gathers bf16 rows (512 B each) + precomputed logits; no dots, no shuffles.
__global__ __launch_bounds__(256) void attn_pull2(
    const u16* __restrict__ featb, const float* __restrict__ glog,
    const int* __restrict__ lostS, const int* __restrict__ retS,
    u16* __restrict__ cleav) {
  int wave = threadIdx.x >> 6, lane = threadIdx.x & 63;
  int n = blockIdx.x * 4 + wave;
  if (n >= N_CLEAV) return;
#pragma unroll
  for (int sg = 0; sg < 2; ++sg) {
    const int* src = sg ? retS : lostS;
    int4 ridx = *(const int4*)(src + n * 4);
    int r[4] = {ridx.x, ridx.y, ridx.z, ridx.w};
    ushort4 x4[4];
    float lg[4];
#pragma unroll
    for (int d = 0; d < 4; ++d) {
      x4[d] = *(const ushort4*)(featb + (size_t)r[d] * F + lane * 4);
      lg[d] = glog[r[d] * 2 + sg];
    }
    float mx = fmaxf(fmaxf(lg[0], lg[1]), fmaxf(lg[2], lg[3]));
    float e0 = __expf(lg[0] - mx), e1 = __expf(lg[1] - mx);
    float e2 = __expf(lg[2] - mx), e3 = __expf(lg[3] - mx);
    float inv = __frcp_rn(e0 + e1 + e2 + e3);
    float a[4] = {e0 * inv, e1 * inv, e2 * inv, e3 * inv};
    float acc[4] = {0.f, 0.f, 0.f, 0.f};
#pragma unroll
    for (int d = 0; d < 4; ++d) {
      const u16* xp = (const u16*)&x4[d];
#pragma unroll
      for (int k = 0; k < 4; k++) acc[k] += a[d] * bf2f(xp[k]);
    }
    u32 lo = (u32)f2bf(acc[0]) | ((u32)f2bf(acc[1]) << 16);
    u32 hi = (u32)f2bf(acc[2]) | ((u32)f2bf(acc[3]) << 16);
    *(uint2*)(cleav + (size_t)n * 512 + sg * 256 + lane * 4) = make_uint2(lo, hi);
  }
}

// ---------------- GEMM: C[M,1024] = A[M,K] * B[1024,K]^T ------------------
// 256x256 tile, BK=64, 8 waves (2M x 4N), 128 KiB LDS double-buffered at
// K-tile granularity. 4 quadrant phases per K-tile (16 MFMA each), per-phase
// {ds_read subtile | 1 half-tile global_load_lds} -> barrier -> lgkmcnt(0)
// -> setprio(1) MFMA setprio(0) -> barrier.  Counted vmcnt(4) only at the
// tile boundary (2 half-tiles of 2 loads stay in flight across it).
// LDS swizzle: physical k-chunk = logical ^ (row&7); staging keeps LDS dest
// linear (global_load_lds) and pre-swizzles the GLOBAL source; reads apply
// the same involution.
// EPI==0: C = acc + bias[n]; EPI==1: C = acc.
template <int EPI, int K>
__global__ __launch_bounds__(512, 2) void gemm256(
    const u16* __restrict__ A, const u16* __restrict__ Bw,
    u16* __restrict__ C, const float* __restrict__ bias,
    int nper, int mstrips_valid) {
  __shared__ u16 sh[2][32768];  // [buf][A:0..16383 | B:16384..32767]
  const int flat = blockIdx.x;
  const int xcd = flat & 7;
  const int w = flat >> 3;
  const int mstrip = xcd * nper + (w >> 2);
  const int nstrip = w & 3;
  if (mstrip >= mstrips_valid) return;
  const int m0 = mstrip * 256;
  const int n0 = nstrip * 256;

  const int tid = threadIdx.x;
  const int lane = tid & 63;
  const int wave = tid >> 6;
  const int quad = lane >> 4;
  const int l16 = lane & 15;
  const int s7 = l16 & 7;
  const int wm2 = wave >> 2;  // 0..1 -> 128-row half
  const int wn4 = wave & 3;   // 0..3 -> 64-col slice

  // read bases (u16 units inside one buffer)
  const int arow = (wm2 * 128 + l16) * 64;
  const int brow = 16384 + (wn4 * 64 + l16) * 64;
  const int coff0 = ((0 + quad) ^ s7) * 8;  // k-step 0 chunk
  const int coff1 = ((4 + quad) ^ s7) * 8;  // k-step 1 chunk

  // staging precompute: chunk c = j*512 + tid; r=c>>3 row, p=c&7 phys chunk
  int srow[2], ssw[2], sdst[2];
#pragma unroll
  for (int j = 0; j < 2; j++) {
    int c = j * 512 + tid;
    int r = c >> 3, p = c & 7;
    srow[j] = r;
    ssw[j] = (p ^ (r & 7)) * 8;              // pre-swizzled global k-offset
    sdst[j] = (j * 512 + (tid & ~63)) * 8;   // wave-uniform; HW adds lane*16B
  }
  const u16* Abase = A + (size_t)m0 * K;
  const u16* Bbase = Bw + (size_t)n0 * K;

  auto stage = [&](int buf, int mat, int h, int kt) {
    const u16* gb = (mat ? Bbase : Abase) + (size_t)(h * 128) * K + kt * 64;
    const u16* lb = &sh[buf][mat * 16384 + h * 8192];
#pragma unroll
    for (int j = 0; j < 2; j++)
      async_copy16(gb + (size_t)srow[j] * K + ssw[j], lb + sdst[j]);
  };

  f32x4 acc[8][4];
#pragma unroll
  for (int i = 0; i < 8; i++)
#pragma unroll
    for (int j = 0; j < 4; j++) acc[i][j] = (f32x4){0.f, 0.f, 0.f, 0.f};

  constexpr int nK = K / 64;
  // prologue: tile0 fully -> buf0; tile1 B halves -> buf1 (A halves follow
  // in-loop at phases 1-2 of tile 0).
  stage(0, 0, 0, 0); stage(0, 0, 1, 0); stage(0, 1, 0, 0); stage(0, 1, 1, 0);
  if (nK > 1) { stage(1, 1, 0, 1); stage(1, 1, 1, 1); }
  __builtin_amdgcn_s_waitcnt(0xF74);  // vmcnt(4): tile0 landed, tile1-B in flight
  __builtin_amdgcn_s_barrier();

  bf16x8 a[4][2], b0[2][2], b1[2][2];
#pragma unroll
  for (int t = 0; t < nK; ++t) {
    const int bsel = t & 1;
    const u16* S = &sh[bsel][0];

    // ---- phase 1: Q(qm=0,qn=0). 12 ds_read_b128; stage A-half0(t+1).
#pragma unroll
    for (int i = 0; i < 4; i++) {
      a[i][0] = *(const bf16x8*)&S[arow + i * 1024 + coff0];
      a[i][1] = *(const bf16x8*)&S[arow + i * 1024 + coff1];
    }
#pragma unroll
    for (int j = 0; j < 2; j++) {
      b0[j][0] = *(const bf16x8*)&S[brow + j * 1024 + coff0];
      b0[j][1] = *(const bf16x8*)&S[brow + j * 1024 + coff1];
    }
    if (t + 1 < nK) stage(bsel ^ 1, 0, 0, t + 1);
    __builtin_amdgcn_s_waitcnt(0xC87F);  // lgkmcnt(8) pre-barrier (12 issued)
    __builtin_amdgcn_s_barrier();
    __builtin_amdgcn_s_waitcnt(0xC07F);  // lgkmcnt(0)
    __builtin_amdgcn_sched_barrier(0);
    __builtin_amdgcn_s_setprio(1);
#pragma unroll
    for (int i = 0; i < 4; i++)
#pragma unroll
      for (int j = 0; j < 2; j++) {
        acc[i][j] = __builtin_amdgcn_mfma_f32_16x16x32_bf16(a[i][0], b0[j][0], acc[i][j], 0, 0, 0);
        acc[i][j] = __builtin_amdgcn_mfma_f32_16x16x32_bf16(a[i][1], b0[j][1], acc[i][j], 0, 0, 0);
      }
    __builtin_amdgcn_s_setprio(0);
    __builtin_amdgcn_s_barrier();

    // ---- phase 2: Q(0,1). 4 ds_read; stage A-half1(t+1).
#pragma unroll
    for (int j = 0; j < 2; j++) {
      b1[j][0] = *(const bf16x8*)&S[brow + (2 + j) * 1024 + coff0];
      b1[j][1] = *(const bf16x8*)&S[brow + (2 + j) * 1024 + coff1];
    }
    if (t + 1 < nK) stage(bsel ^ 1, 0, 1, t + 1);
    __builtin_amdgcn_s_barrier();
    __builtin_amdgcn_s_waitcnt(0xC07F);
    __builtin_amdgcn_sched_barrier(0);
    __builtin_amdgcn_s_setprio(1);
#pragma unroll
    for (int i = 0; i < 4; i++)
#pragma unroll
      for (int j = 0; j < 2; j++) {
        acc[i][2 + j] = __builtin_amdgcn_mfma_f32_16x16x32_bf16(a[i][0], b1[j][0], acc[i][2 + j], 0, 0, 0);
        acc[i][2 + j] = __builtin_amdgcn_mfma_f32_16x16x32_bf16(a[i][1], b1[j][1], acc[i][2 + j], 0, 0, 0);
      }
    __builtin_amdgcn_s_setprio(0);
    __builtin_amdgcn_s_barrier();

    // ---- phase 3: Q(1,0). 8 ds_read (reuse a[]); stage B-half0(t+2)->buf bsel.
#pragma unroll
    for (int i = 0; i < 4; i++) {
      a[i][0] = *(const bf16x8*)&S[arow + (4 + i) * 1024 + coff0];
      a[i][1] = *(const bf16x8*)&S[arow + (4 + i) * 1024 + coff1];
    }
    if (t + 2 < nK) stage(bsel, 1, 0, t + 2);
    __builtin_amdgcn_s_barrier();
    __builtin_amdgcn_s_waitcnt(0xC07F);
    __builtin_amdgcn_sched_barrier(0);
    __builtin_amdgcn_s_setprio(1);
#pragma unroll
    for (int i = 0; i < 4; i++)
#pragma unroll
      for (int j = 0; j < 2; j++) {
        acc[4 + i][j] = __builtin_amdgcn_mfma_f32_16x16x32_bf16(a[i][0], b0[j][0], acc[4 + i][j], 0, 0, 0);
        acc[4 + i][j] = __builtin_amdgcn_mfma_f32_16x16x32_bf16(a[i][1], b0[j][1], acc[4 + i][j], 0, 0, 0);
      }
    __builtin_amdgcn_s_setprio(0);
    __builtin_amdgcn_s_barrier();

    // ---- phase 4: Q(1,1). 0 ds_read; stage B-half1(t+2); boundary vmcnt.
    if (t + 2 < nK) stage(bsel, 1, 1, t + 2);
    __builtin_amdgcn_s_barrier();
    __builtin_amdgcn_s_setprio(1);
#pragma unroll
    for (int i = 0; i < 4; i++)
#pragma unroll
      for (int j = 0; j < 2; j++) {
        acc[4 + i][2 + j] = __builtin_amdgcn_mfma_f32_16x16x32_bf16(a[i][0], b1[j][0], acc[4 + i][2 + j], 0, 0, 0);
        acc[4 + i][2 + j] = __builtin_amdgcn_mfma_f32_16x16x32_bf16(a[i][1], b1[j][1], acc[4 + i][2 + j], 0, 0, 0);
      }
    __builtin_amdgcn_s_setprio(0);
    // all but the 2 newest half-tiles (Bh(t+2)) must be landed before any
    // wave reads buf^1; in the drain tiles (no t+2 stages) drain fully.
    if (t + 2 < nK) __builtin_amdgcn_s_waitcnt(0xF74);  // vmcnt(4)
    else            __builtin_amdgcn_s_waitcnt(0xF70);  // vmcnt(0)
    __builtin_amdgcn_s_barrier();
  }

  // epilogue: C/D layout col=lane&15, row=quad*4+reg
  float badd[4];
#pragma unroll
  for (int j = 0; j < 4; j++)
    badd[j] = (EPI == 0) ? bias[n0 + wn4 * 64 + j * 16 + l16] : 0.f;
#pragma unroll
  for (int i = 0; i < 8; i++) {
    const int mrow = m0 + wm2 * 128 + i * 16 + quad * 4;
#pragma unroll
    for (int j = 0; j < 4; j++) {
      const int n = n0 + wn4 * 64 + j * 16 + l16;
#pragma unroll
      for (int r = 0; r < 4; r++)
        C[(size_t)(mrow + r) * 1024 + n] = f2bf(acc[i][j][r] + badd[j]);
    }
  }
}

// ---------------- K3: LSTM step 1, wave-per-fragment ----------------------
__global__ __launch_bounds__(256) void lstm_step1(
    const u16* __restrict__ P, const int* __restrict__ join,
    u16* __restrict__ h1, u16* __restrict__ c1) {
  int wave = threadIdx.x >> 6, lane = threadIdx.x & 63;
  int m = blockIdx.x * 4 + wave;
  if (m >= N_FRAG) return;
  int j0 = join[2 * m];
  const u16* row = P + (size_t)j0 * 1024 + lane * 4;
  ushort4 iv = *(const ushort4*)(row);
  ushort4 gv = *(const ushort4*)(row + 512);
  ushort4 ov = *(const ushort4*)(row + 768);
  const u16* ivp = (const u16*)&iv;
  const u16* gvp = (const u16*)&gv;
  const u16* ovp = (const u16*)&ov;
  ushort4 h4, c4;
  u16* h4p = (u16*)&h4;
  u16* c4p = (u16*)&c4;
#pragma unroll
  for (int k = 0; k < 4; k++) {
    float c = sigmoidf(bf2f(ivp[k])) * fast_tanh(bf2f(gvp[k]));
    float hv = sigmoidf(bf2f(ovp[k])) * fast_tanh(c);
    h4p[k] = f2bf(hv);
    c4p[k] = f2bf(c);
  }
  *(ushort4*)(h1 + (size_t)m * 256 + lane * 4) = h4;
  *(ushort4*)(c1 + (size_t)m * 256 + lane * 4) = c4;
}

// ------- K5: LSTM step 2 + attention over {h1,h2} + output head -----------
__global__ __launch_bounds__(256) void lstm_step2_attn_out(
    const u16* __restrict__ G2, const u16* __restrict__ P,
    const int* __restrict__ join, const u16* __restrict__ c1,
    const u16* __restrict__ h1b, const float* __restrict__ Wg,
    const float* __restrict__ Wout, const float* __restrict__ bout,
    float* __restrict__ frag_out) {
  int wave = threadIdx.x >> 6, lane = threadIdx.x & 63;
  int m = blockIdx.x * 4 + wave;
  if (m >= N_FRAG) return;
  int j1 = join[2 * m + 1];
  const u16* row = G2 + (size_t)m * 1024 + lane * 4;
  const u16* prow = P + (size_t)j1 * 1024 + lane * 4;
  ushort4 iv = *(const ushort4*)(row);
  ushort4 fv = *(const ushort4*)(row + 256);
  ushort4 gv = *(const ushort4*)(row + 512);
  ushort4 ov = *(const ushort4*)(row + 768);
  ushort4 pi = *(const ushort4*)(prow);
  ushort4 pf = *(const ushort4*)(prow + 256);
  ushort4 pg = *(const ushort4*)(prow + 512);
  ushort4 po = *(const ushort4*)(prow + 768);
  ushort4 c4 = *(const ushort4*)(c1 + (size_t)m * 256 + lane * 4);
  ushort4 h4 = *(const ushort4*)(h1b + (size_t)m * 256 + lane * 4);
  float4 wg = *(const float4*)(Wg + lane * 4);
  const u16* ivp = (const u16*)&iv; const u16* pip = (const u16*)&pi;
  const u16* fvp = (const u16*)&fv; const u16* pfp = (const u16*)&pf;
  const u16* gvp = (const u16*)&gv; const u16* pgp = (const u16*)&pg;
  const u16* ovp = (const u16*)&ov; const u16* pop = (const u16*)&po;
  const u16* c4p = (const u16*)&c4;
  const u16* h4p = (const u16*)&h4;
  const float* wgp = (const float*)&wg;

  float h1v[4], h2v[4];
  float p1 = 0.f, p2 = 0.f;
#pragma unroll
  for (int k = 0; k < 4; k++) {
    float gi = bf2f(ivp[k]) + bf2f(pip[k]);
    float gf = bf2f(fvp[k]) + bf2f(pfp[k]);
    float gg = bf2f(gvp[k]) + bf2f(pgp[k]);
    float go = bf2f(ovp[k]) + bf2f(pop[k]);
    float c2 = sigmoidf(gf) * bf2f(c4p[k]) + sigmoidf(gi) * fast_tanh(gg);
    float h2 = sigmoidf(go) * fast_tanh(c2);
    h2v[k] = h2;
    h1v[k] = bf2f(h4p[k]);
    p1 += h1v[k] * wgp[k];
    p2 += h2 * wgp[k];
  }
#pragma unroll
  for (int off = 32; off; off >>= 1) {
    p1 += __shfl_xor(p1, off);
    p2 += __shfl_xor(p2, off);
  }
  float mx = fmaxf(p1, p2);
  float e1 = __expf(p1 - mx), e2 = __expf(p2 - mx);
  float inv = __frcp_rn(e1 + e2);
  float a1 = e1 * inv, a2 = e2 * inv;

  float acc[8];
#pragma unroll
  for (int t = 0; t < 8; t++) acc[t] = 0.f;
#pragma unroll
  for (int k = 0; k < 4; k++) {
    float frag = a1 * h1v[k] + a2 * h2v[k];
    int h = lane * 4 + k;
    float4 w0 = *(const float4*)(Wout + h * 8);
    float4 w1 = *(const float4*)(Wout + h * 8 + 4);
    acc[0] += frag * w0.x; acc[1] += frag * w0.y;
    acc[2] += frag * w0.z; acc[3] += frag * w0.w;
    acc[4] += frag * w1.x; acc[5] += frag * w1.y;
    acc[6] += frag * w1.z; acc[7] += frag * w1.w;
  }
#pragma unroll
  for (int off = 32; off; off >>= 1)
#pragma unroll
    for (int t = 0; t < 8; t++) acc[t] += __shfl_xor(acc[t], off);
  if (lane == 0) {
    float4 o0, o1;
    o0.x = fmaxf(acc[0] + bout[0], 0.f);
    o0.y = fmaxf(acc[1] + bout[1], 0.f);
    o0.z = fmaxf(acc[2] + bout[2], 0.f);
    o0.w = fmaxf(acc[3] + bout[3], 0.f);
    o1.x = fmaxf(acc[4] + bout[4], 0.f);
    o1.y = fmaxf(acc[5] + bout[5], 0.f);
    o1.z = fmaxf(acc[6] + bout[6], 0.f);
    o1.w = fmaxf(acc[7] + bout[7], 0.f);
    *(float4*)(frag_out + (size_t)m * 8) = o0;
    *(float4*)(frag_out + (size_t)m * 8 + 4) = o1;
  }
}

// ---------------- K6: combine scatter-sum ---------------------------------
__global__ __launch_bounds__(256) void scatter_sum(
    const float* __restrict__ frag_out, const int* __restrict__ comb,
    float* __restrict__ out) {
  int tid = blockIdx.x * 256 + threadIdx.x;
  if (tid >= N_OUT * 8) return;
  int n = tid >> 3, t = tid & 7;
  float s = 0.f;
#pragma unroll
  for (int d = 0; d < 4; d++) {
    int f = comb[n * 4 + d];
    s += frag_out[(size_t)f * 8 + t];
  }
  out[tid] = s;
}

extern "C" void kernel_launch(void* const* d_in, const int* in_sizes, int n_in,
                              void* d_out, int out_size, void* d_ws, size_t ws_size,
                              hipStream_t stream) {
  const float* feature = (const float*)d_in[0];
  const float* WgL = (const float*)d_in[1];
  const float* WgR = (const float*)d_in[2];
  const float* Wih = (const float*)d_in[3];
  const float* Whh = (const float*)d_in[4];
  const float* bih = (const float*)d_in[5];
  const float* bhh = (const float*)d_in[6];
  const float* Wgf = (const float*)d_in[7];
  const float* Wout = (const float*)d_in[8];
  const float* bout = (const float*)d_in[9];
  const int* lostS = (const int*)d_in[10];
  const int* retS = (const int*)d_in[11];
  const int* joinS = (const int*)d_in[12];
  const int* combS = (const int*)d_in[13];
  float* out = (float*)d_out;

  char* ws = (char*)d_ws;
  size_t off = 0;
  auto alloc = [&](size_t bytes) -> char* {
    char* p = ws + off;
    off = (off + bytes + 255) & ~(size_t)255;
    return p;
  };
  u16* Wihb = (u16*)alloc((size_t)1024 * 512 * 2);
  u16* Whhb = (u16*)alloc((size_t)1024 * 256 * 2);
  float* bias = (float*)alloc(1024 * 4);
  u16* P = (u16*)alloc((size_t)M_CLEAV_PAD * 1024 * 2);
  u16* h1 = (u16*)alloc((size_t)N_FRAG * 256 * 2);
  u16* c1 = (u16*)alloc((size_t)N_FRAG * 256 * 2);
  float* frag_out = (float*)alloc((size_t)N_FRAG * 8 * 4);
  char* uni = alloc((size_t)M_CLEAV_PAD * 1024 * 2);  // cleav then gates2
  u16* cleav = (u16*)uni;
  u16* gates2 = (u16*)uni;
  // featb (76.8 MB) + glog (1.2 MB) alias the P region: dead once
  // attn_pull2 completes, before GEMM-1 writes P (stream-ordered).
  u16* featb = P;
  float* glog = (float*)(P + (size_t)N_MONO * F);

  prep_kernel<<<2048, 256, 0, stream>>>(Wih, Whh, bih, bhh, Wihb, Whhb, bias);
  feat_prep<<<(N_MONO + 3) / 4, 256, 0, stream>>>(feature, WgL, WgR, featb, glog);
  attn_pull2<<<N_CLEAV / 4, 256, 0, stream>>>(featb, glog, lostS, retS, cleav);
  // GEMM-1: M=100352=392*256 strips, 49 per XCD, all valid
  gemm256<0, 512><<<1568, 512, 0, stream>>>(cleav, Wihb, P, bias, 49, 392);
  lstm_step1<<<N_FRAG / 4, 256, 0, stream>>>(P, joinS, h1, c1);
  // GEMM-2: M=80000 -> 313 strips of 256 (rows 80000..80127 read c1 garbage,
  // row-independent so harmless; output rows >=80000 never consumed).
  // 320 virtual strips (40/XCD), tail early-exits.
  gemm256<1, 256><<<1280, 512, 0, stream>>>(h1, Whhb, gates2, nullptr, 40, 313);
  lstm_step2_attn_out<<<N_FRAG / 4, 256, 0, stream>>>(
      gates2, P, joinS, c1, h1, Wgf, Wout, bout, frag_out);
  scatter_sum<<<(N_OUT * 8 + 255) / 256, 256, 0, stream>>>(frag_out, combS, out);
}